// Round 1
// baseline (256.422 us; speedup 1.0000x reference)
//
#include <hip/hip_runtime.h>
#include <hip/hip_bf16.h>

typedef __attribute__((ext_vector_type(4))) float f32x4;
typedef __attribute__((ext_vector_type(8))) short s16x8;
typedef __attribute__((ext_vector_type(4))) short s16x4;

#define DEV __device__ __forceinline__

DEV unsigned short f2bf(float f) {
  union { float f; unsigned u; } v; v.f = f;
  unsigned r = v.u + 0x7FFFu + ((v.u >> 16) & 1u);
  return (unsigned short)(r >> 16);
}

// ---------------- projection: Y = X * W^T + b  (bf16 out) ----------------
// X: [M=16384][256] f32, W: [256][256] f32 (row e, k-contig), B: [256] f32
// out_mode 0: Y[row][e] row-major bf16
// out_mode 1: Y[(n*256+e)*4096 + t] (per-batch transposed, n=row>>12, t=row&4095)
__global__ __launch_bounds__(256) void proj_kernel(
    const float* __restrict__ X, const float* __restrict__ W,
    const float* __restrict__ B, unsigned short* __restrict__ Y,
    const int out_mode)
{
  const int row0 = blockIdx.x * 128;
  const int col0 = blockIdx.y * 128;
  const int tid  = threadIdx.x;
  const int lane = tid & 63;
  const int w    = tid >> 6;
  const int wr = w >> 1, wc = w & 1;
  const int l15 = lane & 15, lg = lane >> 4;

  __shared__ unsigned short As[128][40];  // BK=32 + pad 8
  __shared__ unsigned short Bs[128][40];

  f32x4 acc[4][4];
  #pragma unroll
  for (int i = 0; i < 4; ++i)
    #pragma unroll
    for (int j = 0; j < 4; ++j) acc[i][j] = {0.f, 0.f, 0.f, 0.f};

  const int lr = tid >> 3;          // 0..31
  const int lc = (tid & 7) << 2;    // 0,4,..,28

  for (int k0 = 0; k0 < 256; k0 += 32) {
    __syncthreads();
    #pragma unroll
    for (int p = 0; p < 4; ++p) {
      const int r = p * 32 + lr;
      f32x4 a = *reinterpret_cast<const f32x4*>(&X[(size_t)(row0 + r) * 256 + k0 + lc]);
      s16x4 ha;
      ha[0] = (short)f2bf(a[0]); ha[1] = (short)f2bf(a[1]);
      ha[2] = (short)f2bf(a[2]); ha[3] = (short)f2bf(a[3]);
      *reinterpret_cast<s16x4*>(&As[r][lc]) = ha;
      f32x4 b = *reinterpret_cast<const f32x4*>(&W[(size_t)(col0 + r) * 256 + k0 + lc]);
      s16x4 hb;
      hb[0] = (short)f2bf(b[0]); hb[1] = (short)f2bf(b[1]);
      hb[2] = (short)f2bf(b[2]); hb[3] = (short)f2bf(b[3]);
      *reinterpret_cast<s16x4*>(&Bs[r][lc]) = hb;
    }
    __syncthreads();
    s16x8 af[4], bf[4];
    #pragma unroll
    for (int mi = 0; mi < 4; ++mi)
      af[mi] = *reinterpret_cast<const s16x8*>(&As[wr * 64 + mi * 16 + l15][lg * 8]);
    #pragma unroll
    for (int ni = 0; ni < 4; ++ni)
      bf[ni] = *reinterpret_cast<const s16x8*>(&Bs[wc * 64 + ni * 16 + l15][lg * 8]);
    #pragma unroll
    for (int mi = 0; mi < 4; ++mi)
      #pragma unroll
      for (int ni = 0; ni < 4; ++ni)
        acc[mi][ni] = __builtin_amdgcn_mfma_f32_16x16x32_bf16(af[mi], bf[ni], acc[mi][ni], 0, 0, 0);
  }

  #pragma unroll
  for (int ni = 0; ni < 4; ++ni) {
    const int col = col0 + wc * 64 + ni * 16 + l15;
    const float bv = B[col];
    #pragma unroll
    for (int mi = 0; mi < 4; ++mi)
      #pragma unroll
      for (int j = 0; j < 4; ++j) {
        const int row = row0 + wr * 64 + mi * 16 + lg * 4 + j;  // C layout: col=lane&15, row=(lane>>4)*4+j
        const unsigned short h = f2bf(acc[mi][ni][j] + bv);
        if (out_mode == 0) Y[(size_t)row * 256 + col] = h;
        else Y[((size_t)((row >> 12) * 256 + col)) * 4096 + (row & 4095)] = h;
      }
  }
}

// ---------------- flash attention ----------------
// Qb,Kb: [n*4096+t][256] bf16 ; Vt: [n][256][4096] bf16 ; Out: [n*4096+s][256] f32
__global__ __launch_bounds__(256) void attn_kernel(
    const unsigned short* __restrict__ Qb,
    const unsigned short* __restrict__ Kb,
    const unsigned short* __restrict__ Vt,
    float* __restrict__ Out)
{
  // bijective XCD swizzle: 256 blocks -> 8 XCDs x 32 contiguous (same-batch) blocks
  const int o   = blockIdx.x;
  const int bid = (o & 7) * 32 + (o >> 3);
  const int n   = bid >> 6;
  const int q0  = (bid & 63) * 64;

  const int tid  = threadIdx.x;
  const int lane = tid & 63;
  const int w    = tid >> 6;
  const int l15  = lane & 15;
  const int lg   = lane >> 4;

  __shared__ unsigned short Ks[64 * 256];   // [key][d], rows 512B, 16B-chunk XOR swizzle by key&7
  __shared__ unsigned short Vs[256 * 64];   // [d][key], rows 128B, swizzle by d&7
  __shared__ unsigned short Ps[4][16 * 64]; // per-wave P, rows 128B, swizzle by q&7

  // Q fragments in registers: Q[q0 + w*16 + l15][kg*32 + lg*8 + i]
  s16x8 aq[8];
  {
    const size_t qoff = ((size_t)(n * 4096 + q0 + w * 16 + l15)) * 256 + lg * 8;
    #pragma unroll
    for (int kg = 0; kg < 8; ++kg)
      aq[kg] = *reinterpret_cast<const s16x8*>(&Qb[qoff + kg * 32]);
  }

  f32x4 o_acc[16];
  #pragma unroll
  for (int i = 0; i < 16; ++i) o_acc[i] = {0.f, 0.f, 0.f, 0.f};
  float m[4], l[4];
  #pragma unroll
  for (int j = 0; j < 4; ++j) { m[j] = -1e30f; l[j] = 0.0f; }

  const float c = 0.09016844005f;   // (1/sqrt(256)) * log2(e)

  const unsigned short* kbase = Kb + ((size_t)n * 4096) * 256;
  const unsigned short* vbase = Vt + ((size_t)n * 256) * 4096;

  for (int t0 = 0; t0 < 4096; t0 += 64) {
    __syncthreads();  // all waves done reading previous K/V tiles
    // stage K tile: 2048 16B-chunks; wave w owns chunks [w*512, w*512+512)
    #pragma unroll
    for (int it = 0; it < 8; ++it) {
      const int ch  = w * 512 + it * 64 + lane;
      const int key = ch >> 5, dgs = ch & 31;
      const unsigned short* src = kbase + (size_t)(t0 + key) * 256 + ((dgs ^ (key & 7)) * 8);
      __builtin_amdgcn_global_load_lds(
          (const __attribute__((address_space(1))) unsigned int*)src,
          (__attribute__((address_space(3))) unsigned int*)&Ks[(w * 512 + it * 64) * 8],
          16, 0, 0);
    }
    // stage V^T tile
    #pragma unroll
    for (int it = 0; it < 8; ++it) {
      const int ch = w * 512 + it * 64 + lane;
      const int d = ch >> 3, kg = ch & 7;
      const unsigned short* src = vbase + (size_t)d * 4096 + t0 + ((kg ^ (d & 7)) * 8);
      __builtin_amdgcn_global_load_lds(
          (const __attribute__((address_space(1))) unsigned int*)src,
          (__attribute__((address_space(3))) unsigned int*)&Vs[(w * 512 + it * 64) * 8],
          16, 0, 0);
    }
    asm volatile("s_waitcnt vmcnt(0)" ::: "memory");
    __syncthreads();

    // QK^T: S[q][key], q rows = this wave's 16
    f32x4 s[4];
    #pragma unroll
    for (int nt = 0; nt < 4; ++nt) s[nt] = {0.f, 0.f, 0.f, 0.f};
    #pragma unroll
    for (int nt = 0; nt < 4; ++nt) {
      const int key = nt * 16 + l15;
      #pragma unroll
      for (int kg = 0; kg < 8; ++kg) {
        const int dchunk = kg * 4 + lg;
        const s16x8 bk = *reinterpret_cast<const s16x8*>(
            &Ks[key * 256 + ((dchunk ^ (key & 7)) * 8)]);
        s[nt] = __builtin_amdgcn_mfma_f32_16x16x32_bf16(aq[kg], bk, s[nt], 0, 0, 0);
      }
    }

    // online softmax (rows live in 16-lane groups; j indexes the group's 4 rows)
    float tmax[4];
    #pragma unroll
    for (int j = 0; j < 4; ++j)
      tmax[j] = fmaxf(fmaxf(s[0][j], s[1][j]), fmaxf(s[2][j], s[3][j]));
    #pragma unroll
    for (int off = 1; off <= 8; off <<= 1)
      #pragma unroll
      for (int j = 0; j < 4; ++j)
        tmax[j] = fmaxf(tmax[j], __shfl_xor(tmax[j], off));

    float mn[4], sc[4], rs[4];
    #pragma unroll
    for (int j = 0; j < 4; ++j) {
      mn[j] = fmaxf(m[j], tmax[j]);
      sc[j] = exp2f((m[j] - mn[j]) * c);
      rs[j] = 0.0f;
    }
    float p[4][4];
    #pragma unroll
    for (int nt = 0; nt < 4; ++nt)
      #pragma unroll
      for (int j = 0; j < 4; ++j) {
        p[nt][j] = exp2f((s[nt][j] - mn[j]) * c);
        rs[j] += p[nt][j];
      }
    #pragma unroll
    for (int off = 1; off <= 8; off <<= 1)
      #pragma unroll
      for (int j = 0; j < 4; ++j)
        rs[j] += __shfl_xor(rs[j], off);
    #pragma unroll
    for (int j = 0; j < 4; ++j) { l[j] = l[j] * sc[j] + rs[j]; m[j] = mn[j]; }
    #pragma unroll
    for (int dt = 0; dt < 16; ++dt)
      #pragma unroll
      for (int j = 0; j < 4; ++j)
        o_acc[dt][j] *= sc[j];

    // P -> LDS bf16 (C-layout -> A-layout via per-wave buffer, swizzled)
    unsigned short* pw = &Ps[w][0];
    #pragma unroll
    for (int nt = 0; nt < 4; ++nt)
      #pragma unroll
      for (int j = 0; j < 4; ++j) {
        const int q   = lg * 4 + j;
        const int key = nt * 16 + l15;
        pw[q * 64 + (((key >> 3) ^ (q & 7)) * 8) + (key & 7)] = f2bf(p[nt][j]);
      }

    // PV: O[q][d] += P[q][key] * V[key][d]
    #pragma unroll
    for (int kk = 0; kk < 2; ++kk) {
      const int kchunk = kk * 4 + lg;
      const s16x8 ap = *reinterpret_cast<const s16x8*>(
          &pw[l15 * 64 + ((kchunk ^ (l15 & 7)) * 8)]);
      #pragma unroll
      for (int dt = 0; dt < 16; ++dt) {
        const int d = dt * 16 + l15;
        const s16x8 bv = *reinterpret_cast<const s16x8*>(
            &Vs[d * 64 + ((kchunk ^ (d & 7)) * 8)]);
        o_acc[dt] = __builtin_amdgcn_mfma_f32_16x16x32_bf16(ap, bv, o_acc[dt], 0, 0, 0);
      }
    }
  }

  // epilogue: y = O / l, f32 out
  #pragma unroll
  for (int j = 0; j < 4; ++j) {
    const float inv = 1.0f / l[j];
    const size_t rowoff = ((size_t)(n * 4096 + q0 + w * 16 + lg * 4 + j)) * 256;
    #pragma unroll
    for (int dt = 0; dt < 16; ++dt)
      Out[rowoff + dt * 16 + l15] = o_acc[dt][j] * inv;
  }
}

extern "C" void kernel_launch(void* const* d_in, const int* in_sizes, int n_in,
                              void* d_out, int out_size, void* d_ws, size_t ws_size,
                              hipStream_t stream) {
  const float* query = (const float*)d_in[0];
  const float* key   = (const float*)d_in[1];
  const float* value = (const float*)d_in[2];
  const float* Wq    = (const float*)d_in[3];
  const float* bq    = (const float*)d_in[4];
  const float* Wk    = (const float*)d_in[5];
  const float* bk    = (const float*)d_in[6];
  const float* Wv    = (const float*)d_in[7];
  const float* bv    = (const float*)d_in[8];
  float* out = (float*)d_out;

  unsigned short* qb = (unsigned short*)d_ws;              // [16384][256] bf16
  unsigned short* kb = qb + (size_t)16384 * 256;           // [16384][256] bf16
  unsigned short* vt = kb + (size_t)16384 * 256;           // [4][256][4096] bf16
  (void)in_sizes; (void)n_in; (void)out_size; (void)ws_size;

  dim3 pgrid(128, 2);
  proj_kernel<<<pgrid, 256, 0, stream>>>(query, Wq, bq, qb, 0);
  proj_kernel<<<pgrid, 256, 0, stream>>>(key,   Wk, bk, kb, 0);
  proj_kernel<<<pgrid, 256, 0, stream>>>(value, Wv, bv, vt, 1);
  attn_kernel<<<dim3(256), 256, 0, stream>>>(qb, kb, vt, out);
}

// Round 2
// 193.834 us; speedup vs baseline: 1.3229x; 1.3229x over previous
//
#include <hip/hip_runtime.h>
#include <hip/hip_bf16.h>

typedef __attribute__((ext_vector_type(4))) float f32x4;
typedef __attribute__((ext_vector_type(8))) short s16x8;
typedef __attribute__((ext_vector_type(4))) short s16x4;

#define DEV __device__ __forceinline__

DEV unsigned short f2bf(float f) {
  union { float f; unsigned u; } v; v.f = f;
  unsigned r = v.u + 0x7FFFu + ((v.u >> 16) & 1u);
  return (unsigned short)(r >> 16);
}

// ---------------- fused QKV projection: Y = X * W^T + b (bf16 out) ----------------
__global__ __launch_bounds__(256) void proj_kernel(
    const float* __restrict__ Qx, const float* __restrict__ Kx, const float* __restrict__ Vx,
    const float* __restrict__ Wq, const float* __restrict__ bq,
    const float* __restrict__ Wk, const float* __restrict__ bk,
    const float* __restrict__ Wv, const float* __restrict__ bv,
    unsigned short* __restrict__ qb, unsigned short* __restrict__ kb,
    unsigned short* __restrict__ vt)
{
  const int z = blockIdx.z;
  const float* X = (z == 0) ? Qx : (z == 1) ? Kx : Vx;
  const float* W = (z == 0) ? Wq : (z == 1) ? Wk : Wv;
  const float* B = (z == 0) ? bq : (z == 1) ? bk : bv;
  unsigned short* Y = (z == 0) ? qb : (z == 1) ? kb : vt;
  const int out_mode = (z == 2);

  const int row0 = blockIdx.x * 128;
  const int col0 = blockIdx.y * 128;
  const int tid  = threadIdx.x;
  const int lane = tid & 63;
  const int w    = tid >> 6;
  const int wr = w >> 1, wc = w & 1;
  const int l15 = lane & 15, lg = lane >> 4;

  __shared__ unsigned short As[128][40];
  __shared__ unsigned short Bs[128][40];

  f32x4 acc[4][4];
  #pragma unroll
  for (int i = 0; i < 4; ++i)
    #pragma unroll
    for (int j = 0; j < 4; ++j) acc[i][j] = {0.f, 0.f, 0.f, 0.f};

  const int lr = tid >> 3;
  const int lc = (tid & 7) << 2;

  for (int k0 = 0; k0 < 256; k0 += 32) {
    __syncthreads();
    #pragma unroll
    for (int p = 0; p < 4; ++p) {
      const int r = p * 32 + lr;
      f32x4 a = *reinterpret_cast<const f32x4*>(&X[(size_t)(row0 + r) * 256 + k0 + lc]);
      s16x4 ha;
      ha[0] = (short)f2bf(a[0]); ha[1] = (short)f2bf(a[1]);
      ha[2] = (short)f2bf(a[2]); ha[3] = (short)f2bf(a[3]);
      *reinterpret_cast<s16x4*>(&As[r][lc]) = ha;
      f32x4 b = *reinterpret_cast<const f32x4*>(&W[(size_t)(col0 + r) * 256 + k0 + lc]);
      s16x4 hb;
      hb[0] = (short)f2bf(b[0]); hb[1] = (short)f2bf(b[1]);
      hb[2] = (short)f2bf(b[2]); hb[3] = (short)f2bf(b[3]);
      *reinterpret_cast<s16x4*>(&Bs[r][lc]) = hb;
    }
    __syncthreads();
    s16x8 af[4], bf[4];
    #pragma unroll
    for (int mi = 0; mi < 4; ++mi)
      af[mi] = *reinterpret_cast<const s16x8*>(&As[wr * 64 + mi * 16 + l15][lg * 8]);
    #pragma unroll
    for (int ni = 0; ni < 4; ++ni)
      bf[ni] = *reinterpret_cast<const s16x8*>(&Bs[wc * 64 + ni * 16 + l15][lg * 8]);
    #pragma unroll
    for (int mi = 0; mi < 4; ++mi)
      #pragma unroll
      for (int ni = 0; ni < 4; ++ni)
        acc[mi][ni] = __builtin_amdgcn_mfma_f32_16x16x32_bf16(af[mi], bf[ni], acc[mi][ni], 0, 0, 0);
  }

  #pragma unroll
  for (int ni = 0; ni < 4; ++ni) {
    const int col = col0 + wc * 64 + ni * 16 + l15;
    const float bv_ = B[col];
    #pragma unroll
    for (int mi = 0; mi < 4; ++mi)
      #pragma unroll
      for (int j = 0; j < 4; ++j) {
        const int row = row0 + wr * 64 + mi * 16 + lg * 4 + j;
        const unsigned short h = f2bf(acc[mi][ni][j] + bv_);
        if (out_mode == 0) Y[(size_t)row * 256 + col] = h;
        else Y[((size_t)((row >> 12) * 256 + col)) * 4096 + (row & 4095)] = h;
      }
  }
}

// ---------------- flash attention, 8 waves = 4 q-groups x 2 T-parity groups ----------------
// KVBLK=32, double-buffered K/V per parity, counted vmcnt, in-LDS partial merge.
#define NT 64   // tiles per parity group: 4096 / 32 / 2

__global__ __launch_bounds__(512, 2) void attn_kernel(
    const unsigned short* __restrict__ Qb,
    const unsigned short* __restrict__ Kb,
    const unsigned short* __restrict__ Vt,
    float* __restrict__ Out)
{
  __shared__ __align__(16) unsigned short KsA[4][32 * 256];  // [g*2+buf][key][d] swz
  __shared__ __align__(16) unsigned short VsA[4][256 * 32];  // [g*2+buf][d][key] swz
  __shared__ __align__(16) unsigned short Ps[8][16 * 32];    // per-wave P, swz

  const int o   = blockIdx.x;
  const int bid = (o & 7) * 32 + (o >> 3);   // XCD swizzle (256 % 8 == 0, bijective)
  const int n   = bid >> 6;
  const int q0  = (bid & 63) * 64;

  const int tid  = threadIdx.x;
  const int lane = tid & 63;
  const int w    = tid >> 6;   // 0..7
  const int wq   = w & 3;      // q-group
  const int g    = w >> 2;     // T-parity group
  const int l15  = lane & 15;
  const int lg   = lane >> 4;

  const unsigned short* kbase = Kb + ((size_t)n * 4096) * 256;
  const unsigned short* vbase = Vt + ((size_t)n * 256) * 4096;

  // per-lane staging source pointers for this parity group's first tile (t0 = g*32)
  const unsigned short* srcK[4];
  const unsigned short* srcV[4];
  #pragma unroll
  for (int it = 0; it < 4; ++it) {
    const int c   = it * 256 + wq * 64 + lane;
    const int key = c >> 5, pos = c & 31;
    srcK[it] = kbase + (size_t)(g * 32 + key) * 256 + ((pos ^ ((key & 7) << 2)) * 8);
    const int d = c >> 2, vpos = c & 3;
    srcV[it] = vbase + (size_t)d * 4096 + g * 32 + ((vpos ^ ((d >> 1) & 3)) * 8);
  }

  // Q fragments: Q[q0 + wq*16 + l15][kg*32 + lg*8 + i]
  s16x8 aq[8];
  {
    const size_t qoff = ((size_t)(n * 4096 + q0 + wq * 16 + l15)) * 256 + lg * 8;
    #pragma unroll
    for (int kg = 0; kg < 8; ++kg)
      aq[kg] = *reinterpret_cast<const s16x8*>(&Qb[qoff + kg * 32]);
  }

  f32x4 o_acc[16];
  #pragma unroll
  for (int i = 0; i < 16; ++i) o_acc[i] = {0.f, 0.f, 0.f, 0.f};
  float m[4], l[4];
  #pragma unroll
  for (int j = 0; j < 4; ++j) { m[j] = -1e30f; l[j] = 0.0f; }

  const float c = 0.09016844005f;   // (1/sqrt(256)) * log2(e)
  const float TH = 8.0f / c;        // defer-max threshold in raw-score units

  #define STAGE(BUF)                                                                  \
    do {                                                                              \
      unsigned short* kd = &KsA[g * 2 + (BUF)][0];                                    \
      unsigned short* vd = &VsA[g * 2 + (BUF)][0];                                    \
      _Pragma("unroll")                                                               \
      for (int it = 0; it < 4; ++it) {                                                \
        __builtin_amdgcn_global_load_lds(                                             \
            (const __attribute__((address_space(1))) unsigned int*)srcK[it],          \
            (__attribute__((address_space(3))) unsigned int*)&kd[(it * 256 + wq * 64) * 8], \
            16, 0, 0);                                                                \
        srcK[it] += 64 * 256;                                                         \
      }                                                                               \
      _Pragma("unroll")                                                               \
      for (int it = 0; it < 4; ++it) {                                                \
        __builtin_amdgcn_global_load_lds(                                             \
            (const __attribute__((address_space(1))) unsigned int*)srcV[it],          \
            (__attribute__((address_space(3))) unsigned int*)&vd[(it * 256 + wq * 64) * 8], \
            16, 0, 0);                                                                \
        srcV[it] += 64;                                                               \
      }                                                                               \
    } while (0)

  STAGE(0);   // prologue: tile 0 of this parity group

  for (int i = 0; i < NT; ++i) {
    // B1: all waves finished compute(i-1) -> buf[(i+1)&1] reusable
    __builtin_amdgcn_s_barrier();
    __builtin_amdgcn_sched_barrier(0);
    if (i + 1 < NT) {
      STAGE((i + 1) & 1);
      asm volatile("s_waitcnt vmcnt(8)" ::: "memory");  // tile i landed; i+1 stays in flight
    } else {
      asm volatile("s_waitcnt vmcnt(0)" ::: "memory");
    }
    __builtin_amdgcn_sched_barrier(0);
    __builtin_amdgcn_s_barrier();   // B2: everyone's tile-i data visible
    __builtin_amdgcn_sched_barrier(0);

    const unsigned short* Kt = &KsA[g * 2 + (i & 1)][0];
    const unsigned short* Vw = &VsA[g * 2 + (i & 1)][0];

    // QK^T
    f32x4 s[2];
    s[0] = {0.f, 0.f, 0.f, 0.f}; s[1] = {0.f, 0.f, 0.f, 0.f};
    #pragma unroll
    for (int nt = 0; nt < 2; ++nt) {
      const int key = nt * 16 + l15;
      #pragma unroll
      for (int kg = 0; kg < 8; ++kg) {
        const int dchunk = kg * 4 + lg;
        const s16x8 bk = *reinterpret_cast<const s16x8*>(
            &Kt[key * 256 + ((dchunk ^ ((key & 7) << 2)) * 8)]);
        s[nt] = __builtin_amdgcn_mfma_f32_16x16x32_bf16(aq[kg], bk, s[nt], 0, 0, 0);
      }
    }

    // online softmax with defer-max
    float tmax[4];
    #pragma unroll
    for (int j = 0; j < 4; ++j) tmax[j] = fmaxf(s[0][j], s[1][j]);
    #pragma unroll
    for (int off = 1; off <= 8; off <<= 1)
      #pragma unroll
      for (int j = 0; j < 4; ++j)
        tmax[j] = fmaxf(tmax[j], __shfl_xor(tmax[j], off));

    bool need = false;
    #pragma unroll
    for (int j = 0; j < 4; ++j) need |= (tmax[j] > m[j] + TH);
    if (__any((int)need)) {
      float scv[4];
      #pragma unroll
      for (int j = 0; j < 4; ++j) {
        const float mn = fmaxf(m[j], tmax[j]);
        scv[j] = exp2f((m[j] - mn) * c);
        l[j] *= scv[j];
        m[j] = mn;
      }
      #pragma unroll
      for (int dt = 0; dt < 16; ++dt)
        #pragma unroll
        for (int j = 0; j < 4; ++j) o_acc[dt][j] *= scv[j];
    }

    float p0[4], p1[4], rs[4];
    #pragma unroll
    for (int j = 0; j < 4; ++j) {
      p0[j] = exp2f((s[0][j] - m[j]) * c);
      p1[j] = exp2f((s[1][j] - m[j]) * c);
      rs[j] = p0[j] + p1[j];
    }
    #pragma unroll
    for (int off = 1; off <= 8; off <<= 1)
      #pragma unroll
      for (int j = 0; j < 4; ++j) rs[j] += __shfl_xor(rs[j], off);
    #pragma unroll
    for (int j = 0; j < 4; ++j) l[j] += rs[j];

    // P -> LDS (C-layout -> A-layout), swizzled
    unsigned short* pw = &Ps[w][0];
    #pragma unroll
    for (int nt = 0; nt < 2; ++nt)
      #pragma unroll
      for (int j = 0; j < 4; ++j) {
        const int q   = lg * 4 + j;
        const int key = nt * 16 + l15;
        const float pv = (nt == 0) ? p0[j] : p1[j];
        pw[q * 32 + (((key >> 3) ^ ((q >> 1) & 3)) * 8) + (key & 7)] = f2bf(pv);
      }

    // PV
    const s16x8 ap = *reinterpret_cast<const s16x8*>(
        &pw[l15 * 32 + ((lg ^ ((l15 >> 1) & 3)) * 8)]);
    #pragma unroll
    for (int dt = 0; dt < 16; ++dt) {
      const int d = dt * 16 + l15;
      const s16x8 bv = *reinterpret_cast<const s16x8*>(
          &Vw[d * 32 + ((lg ^ ((d >> 1) & 3)) * 8)]);
      o_acc[dt] = __builtin_amdgcn_mfma_f32_16x16x32_bf16(ap, bv, o_acc[dt], 0, 0, 0);
    }
  }

  // ---- merge the two parity groups' partials through LDS ----
  __syncthreads();
  float* cbO  = (float*)&KsA[0][0];   // 64 KB = 4 waves * 64 lanes * 16 f32x4
  float* cbML = (float*)&Ps[0][0];    // 8 KB  = 4 waves * 64 lanes * 8 f32
  if (g == 1) {
    f32x4* ob = (f32x4*)cbO + ((wq * 64 + lane) * 16);
    #pragma unroll
    for (int dt = 0; dt < 16; ++dt) ob[dt ^ (lane & 15)] = o_acc[dt];
    float* ml = &cbML[(wq * 64 + lane) * 8];
    #pragma unroll
    for (int j = 0; j < 4; ++j) { ml[j] = m[j]; ml[4 + j] = l[j]; }
  }
  __syncthreads();
  if (g == 0) {
    const f32x4* ob = (const f32x4*)cbO + ((wq * 64 + lane) * 16);
    const float* ml = &cbML[(wq * 64 + lane) * 8];
    float sc0[4], sc1[4], inv[4];
    #pragma unroll
    for (int j = 0; j < 4; ++j) {
      const float m1 = ml[j], l1 = ml[4 + j];
      const float mf = fmaxf(m[j], m1);
      sc0[j] = exp2f((m[j] - mf) * c);
      sc1[j] = exp2f((m1 - mf) * c);
      inv[j] = 1.0f / (l[j] * sc0[j] + l1 * sc1[j]);
    }
    #pragma unroll
    for (int dt = 0; dt < 16; ++dt) {
      const f32x4 o1 = ob[dt ^ (lane & 15)];
      #pragma unroll
      for (int j = 0; j < 4; ++j) {
        const size_t row = (size_t)(n * 4096 + q0 + wq * 16 + lg * 4 + j);
        Out[row * 256 + dt * 16 + l15] = (o_acc[dt][j] * sc0[j] + o1[j] * sc1[j]) * inv[j];
      }
    }
  }
  #undef STAGE
}

extern "C" void kernel_launch(void* const* d_in, const int* in_sizes, int n_in,
                              void* d_out, int out_size, void* d_ws, size_t ws_size,
                              hipStream_t stream) {
  const float* query = (const float*)d_in[0];
  const float* key   = (const float*)d_in[1];
  const float* value = (const float*)d_in[2];
  const float* Wq    = (const float*)d_in[3];
  const float* bq    = (const float*)d_in[4];
  const float* Wk    = (const float*)d_in[5];
  const float* bk    = (const float*)d_in[6];
  const float* Wv    = (const float*)d_in[7];
  const float* bv    = (const float*)d_in[8];
  float* out = (float*)d_out;

  unsigned short* qb = (unsigned short*)d_ws;              // [16384][256] bf16
  unsigned short* kb = qb + (size_t)16384 * 256;           // [16384][256] bf16
  unsigned short* vt = kb + (size_t)16384 * 256;           // [4][256][4096] bf16
  (void)in_sizes; (void)n_in; (void)out_size; (void)ws_size;

  proj_kernel<<<dim3(128, 2, 3), 256, 0, stream>>>(query, key, value,
                                                   Wq, bq, Wk, bk, Wv, bv,
                                                   qb, kb, vt);
  attn_kernel<<<dim3(256), 512, 0, stream>>>(qb, kb, vt, out);
}